// Round 3
// baseline (152.611 us; speedup 1.0000x reference)
//
#include <hip/hip_runtime.h>
#include <hip/hip_fp16.h>

#define HID 2048
#define FIVEH 10240
#define INP 128
#define BATCH 2048

typedef _Float16 half8 __attribute__((ext_vector_type(8)));
typedef float f32x4 __attribute__((ext_vector_type(4)));

// load 8 consecutive f32, convert to half8 in-register
__device__ __forceinline__ half8 cvt8(const float* p) {
  float4 a = *(const float4*)p;
  float4 b = *(const float4*)(p + 4);
  half8 h;
  h[0] = (_Float16)a.x; h[1] = (_Float16)a.y; h[2] = (_Float16)a.z; h[3] = (_Float16)a.w;
  h[4] = (_Float16)b.x; h[5] = (_Float16)b.y; h[6] = (_Float16)b.z; h[7] = (_Float16)b.w;
  return h;
}

// ---------------- GEMM v3 (unchanged, verified): LDS-staged W, transposed epilogue ----
#define WSTRIDE 136
__global__ __launch_bounds__(256) void gemm_up(const float* __restrict__ A,
                                               const float* __restrict__ W,
                                               const float* __restrict__ bias,
                                               _Float16* __restrict__ up16,
                                               int row0, int nrows) {
  __shared__ _Float16 Ws[128 * WSTRIDE];
  int tid = threadIdx.x, wave = tid >> 6, lane = tid & 63;
  int bx = blockIdx.x;
  int by = blockIdx.y;
  int nl = lane & 15, quad = lane >> 4;

  {
    const float* src = W + (size_t)(bx * 128) * INP;
#pragma unroll
    for (int it = 0; it < 8; ++it) {
      int n = (it * 256 + tid) * 8;
      int col = n >> 7, k = n & 127;
      *(half8*)(Ws + col * WSTRIDE + k) = cvt8(src + n);
    }
  }

  half8 af[2][4];
  int rowbase = row0 + by * 128 + wave * 32;
#pragma unroll
  for (int mt = 0; mt < 2; ++mt) {
    const float* ar = A + (size_t)(rowbase + mt * 16 + nl) * INP + quad * 8;
#pragma unroll
    for (int ks = 0; ks < 4; ++ks) af[mt][ks] = cvt8(ar + ks * 32);
  }
  __syncthreads();

  f32x4 acc[2][8];
#pragma unroll
  for (int nt = 0; nt < 8; ++nt) {
    half8 bf[4];
#pragma unroll
    for (int ks = 0; ks < 4; ++ks)
      bf[ks] = *(const half8*)(Ws + (nt * 16 + nl) * WSTRIDE + quad * 8 + ks * 32);
#pragma unroll
    for (int mt = 0; mt < 2; ++mt) {
      f32x4 a = {0.f, 0.f, 0.f, 0.f};
#pragma unroll
      for (int ks = 0; ks < 4; ++ks)
        a = __builtin_amdgcn_mfma_f32_16x16x32_f16(af[mt][ks], bf[ks], a, 0, 0, 0);
      acc[mt][nt] = a;
    }
  }
  __syncthreads();

#pragma unroll
  for (int nt = 0; nt < 8; ++nt) {
    float bv = bias[bx * 128 + nt * 16 + nl];
#pragma unroll
    for (int mt = 0; mt < 2; ++mt) {
      int rl = wave * 32 + mt * 16 + quad * 4;
#pragma unroll
      for (int r = 0; r < 4; ++r)
        Ws[(rl + r) * WSTRIDE + nt * 16 + nl] = (_Float16)(acc[mt][nt][r] + bv);
    }
  }
  __syncthreads();

#pragma unroll
  for (int it = 0; it < 8; ++it) {
    int v = it * 256 + tid;
    int r = v >> 4, c8 = (v & 15) * 8;
    *(half8*)(up16 + (size_t)(by * 128 + r) * FIVEH + bx * 128 + c8) =
        *(const half8*)(Ws + r * WSTRIDE + c8);
  }
}

// ---------------- f16-LDS helpers ----------------
__device__ __forceinline__ float2 h2ld(const __half2* p, int i) {
  return __half22float2(p[i]);
}
__device__ __forceinline__ void h2st(__half2* p, int i, float x, float y) {
  p[i] = __floats2half2_rn(x, y);
}

// ---------------- fused FFT pieces (same Stockham math, verified R1/R2) ----------
// HEAD: radix-2 (stride 1024) + radix-4 L=2, entirely in registers.
__device__ __forceinline__ void fft_head(const float2 v[8], __half2* dst, int tid, float sgn) {
  const float R2 = 0.70710678118654752f;
  float2 o[8];
  {  // i' = 2*tid : x_j = v[j] + v[j+4], k=0 (unit twiddles)
    float x0r = v[0].x + v[4].x, x0i = v[0].y + v[4].y;
    float x1r = v[1].x + v[5].x, x1i = v[1].y + v[5].y;
    float x2r = v[2].x + v[6].x, x2i = v[2].y + v[6].y;
    float x3r = v[3].x + v[7].x, x3i = v[3].y + v[7].y;
    float t0r = x0r + x2r, t0i = x0i + x2i, t1r = x0r - x2r, t1i = x0i - x2i;
    float t2r = x1r + x3r, t2i = x1i + x3i, t3r = x1r - x3r, t3i = x1i - x3i;
    o[0].x = t0r + t2r;       o[0].y = t0i + t2i;
    o[4].x = t0r - t2r;       o[4].y = t0i - t2i;
    o[2].x = t1r - sgn * t3i; o[2].y = t1i + sgn * t3r;
    o[6].x = t1r + sgn * t3i; o[6].y = t1i - sgn * t3r;
  }
  {  // i' = 2*tid+1 : k=1 -> c1=R2,s1=sgn*R2; c2=0,s2=sgn; c3=-R2,s3=sgn*R2
    float x0r = v[0].x - v[4].x, x0i = v[0].y - v[4].y;
    float x1r = v[1].x - v[5].x, x1i = v[1].y - v[5].y;
    float x2r = v[2].x - v[6].x, x2i = v[2].y - v[6].y;
    float x3r = v[3].x - v[7].x, x3i = v[3].y - v[7].y;
    float y1r = (x1r - sgn * x1i) * R2,  y1i = (sgn * x1r + x1i) * R2;
    float y2r = -sgn * x2i,              y2i = sgn * x2r;
    float y3r = -(x3r + sgn * x3i) * R2, y3i = (sgn * x3r - x3i) * R2;
    float t0r = x0r + y2r, t0i = x0i + y2i, t1r = x0r - y2r, t1i = x0i - y2i;
    float t2r = y1r + y3r, t2i = y1i + y3i, t3r = y1r - y3r, t3i = y1i - y3i;
    o[1].x = t0r + t2r;       o[1].y = t0i + t2i;
    o[5].x = t0r - t2r;       o[5].y = t0i - t2i;
    o[3].x = t1r - sgn * t3i; o[3].y = t1i + sgn * t3r;
    o[7].x = t1r + sgn * t3i; o[7].y = t1i - sgn * t3r;
  }
  __half2* base = dst + 8 * tid;  // contiguous 32B -> merged b128 writes
#pragma unroll
  for (int j = 0; j < 8; ++j) h2st(base, j, o[j].x, o[j].y);
}

// MID (single-row, used by fallback): radix-4 LDS pass, twiddle hoisted.
template <int L>
__device__ __forceinline__ void fft_mid(const __half2* __restrict__ src,
                                        __half2* __restrict__ dst, int tid, float sgn) {
  static_assert(256 % L == 0, "twiddle hoist requires 256 % L == 0");
  const int k = tid & (L - 1);
  float s1, c1;
  __sincosf(sgn * (1.5707963267948966f / (float)L) * (float)k, &s1, &c1);
  float c2 = c1 * c1 - s1 * s1, s2 = 2.f * c1 * s1;
  float c3 = c1 * c2 - s1 * s2, s3 = c1 * s2 + s1 * c2;
#pragma unroll
  for (int t = 0; t < 2; ++t) {
    int i = tid + (t << 8);
    int base4 = ((i - k) << 2) + k;
    float2 x0 = h2ld(src, i),        x1 = h2ld(src, i + 512);
    float2 x2 = h2ld(src, i + 1024), x3 = h2ld(src, i + 1536);
    float y1r = x1.x * c1 - x1.y * s1, y1i = x1.x * s1 + x1.y * c1;
    float y2r = x2.x * c2 - x2.y * s2, y2i = x2.x * s2 + x2.y * c2;
    float y3r = x3.x * c3 - x3.y * s3, y3i = x3.x * s3 + x3.y * c3;
    float t0r = x0.x + y2r, t0i = x0.y + y2i;
    float t1r = x0.x - y2r, t1i = x0.y - y2i;
    float t2r = y1r + y3r, t2i = y1i + y3i;
    float t3r = y1r - y3r, t3i = y1i - y3i;
    h2st(dst, base4,         t0r + t2r, t0i + t2i);
    h2st(dst, base4 + 2 * L, t0r - t2r, t0i - t2i);
    h2st(dst, base4 + L,     t1r - sgn * t3i, t1i + sgn * t3r);
    h2st(dst, base4 + 3 * L, t1r + sgn * t3i, t1i - sgn * t3r);
  }
}

// MID (2-row): twiddle sincos computed ONCE, applied to both rows' buffers.
template <int L>
__device__ __forceinline__ void fft_mid2(const __half2 (*__restrict__ src)[HID],
                                         __half2 (*__restrict__ dst)[HID],
                                         int tid, float sgn) {
  static_assert(256 % L == 0, "twiddle hoist requires 256 % L == 0");
  const int k = tid & (L - 1);
  float s1, c1;
  __sincosf(sgn * (1.5707963267948966f / (float)L) * (float)k, &s1, &c1);
  float c2 = c1 * c1 - s1 * s1, s2 = 2.f * c1 * s1;
  float c3 = c1 * c2 - s1 * s2, s3 = c1 * s2 + s1 * c2;
#pragma unroll
  for (int r = 0; r < 2; ++r) {
#pragma unroll
    for (int t = 0; t < 2; ++t) {
      int i = tid + (t << 8);
      int base4 = ((i - k) << 2) + k;
      float2 x0 = h2ld(src[r], i),        x1 = h2ld(src[r], i + 512);
      float2 x2 = h2ld(src[r], i + 1024), x3 = h2ld(src[r], i + 1536);
      float y1r = x1.x * c1 - x1.y * s1, y1i = x1.x * s1 + x1.y * c1;
      float y2r = x2.x * c2 - x2.y * s2, y2i = x2.x * s2 + x2.y * c2;
      float y3r = x3.x * c3 - x3.y * s3, y3i = x3.x * s3 + x3.y * c3;
      float t0r = x0.x + y2r, t0i = x0.y + y2i;
      float t1r = x0.x - y2r, t1i = x0.y - y2i;
      float t2r = y1r + y3r, t2i = y1i + y3i;
      float t3r = y1r - y3r, t3i = y1i - y3i;
      h2st(dst[r], base4,         t0r + t2r, t0i + t2i);
      h2st(dst[r], base4 + 2 * L, t0r - t2r, t0i - t2i);
      h2st(dst[r], base4 + L,     t1r - sgn * t3i, t1i + sgn * t3r);
      h2st(dst[r], base4 + 3 * L, t1r + sgn * t3i, t1i - sgn * t3r);
    }
  }
}

// TAIL twiddles (L=512), shared across rows: depends only on tid.
struct TailTw { float c1[2], s1[2], c2[2], s2[2], c3[2], s3[2]; };
__device__ __forceinline__ TailTw tail_tw(int tid, float sgn) {
  TailTw w;
#pragma unroll
  for (int t = 0; t < 2; ++t) {
    int i = tid + (t << 8);
    float s1, c1;
    __sincosf(sgn * (1.5707963267948966f / 512.f) * (float)i, &s1, &c1);
    w.c1[t] = c1; w.s1[t] = s1;
    w.c2[t] = c1 * c1 - s1 * s1; w.s2[t] = 2.f * c1 * s1;
    w.c3[t] = c1 * w.c2[t] - s1 * w.s2[t]; w.s3[t] = c1 * w.s2[t] + s1 * w.c2[t];
  }
  return w;
}

// TAIL (one row, precomputed twiddles): final radix-4 pass into registers.
__device__ __forceinline__ void fft_tail_row(const __half2* __restrict__ src, float2 h[8],
                                             int tid, float sgn, const TailTw& w) {
#pragma unroll
  for (int t = 0; t < 2; ++t) {
    int i = tid + (t << 8);
    float2 x0 = h2ld(src, i),        x1 = h2ld(src, i + 512);
    float2 x2 = h2ld(src, i + 1024), x3 = h2ld(src, i + 1536);
    float y1r = x1.x * w.c1[t] - x1.y * w.s1[t], y1i = x1.x * w.s1[t] + x1.y * w.c1[t];
    float y2r = x2.x * w.c2[t] - x2.y * w.s2[t], y2i = x2.x * w.s2[t] + x2.y * w.c2[t];
    float y3r = x3.x * w.c3[t] - x3.y * w.s3[t], y3i = x3.x * w.s3[t] + x3.y * w.c3[t];
    float t0r = x0.x + y2r, t0i = x0.y + y2i;
    float t1r = x0.x - y2r, t1i = x0.y - y2i;
    float t2r = y1r + y3r, t2i = y1i + y3i;
    float t3r = y1r - y3r, t3i = y1i - y3i;
    h[t].x     = t0r + t2r;       h[t].y     = t0i + t2i;
    h[t + 4].x = t0r - t2r;       h[t + 4].y = t0i - t2i;
    h[t + 2].x = t1r - sgn * t3i; h[t + 2].y = t1i + sgn * t3r;
    h[t + 6].x = t1r + sgn * t3i; h[t + 6].y = t1i - sgn * t3r;
  }
}

// TAIL (single-row, fallback path)
__device__ __forceinline__ void fft_tail(const __half2* __restrict__ src, float2 h[8],
                                         int tid, float sgn) {
  TailTw w = tail_tw(tid, sgn);
  fft_tail_row(src, h, tid, sgn, w);
}

// wave shfl reduce + tiny LDS combine. Caller provides a PRIVATE red buffer per call
// site, so no trailing barrier is needed (single sync per reduction).
__device__ __forceinline__ void block_reduce2(float& pr, float& pi,
                                              float* redr, float* redi, int tid) {
  for (int off = 32; off > 0; off >>= 1) {
    pr += __shfl_down(pr, off, 64);
    pi += __shfl_down(pi, off, 64);
  }
  if ((tid & 63) == 0) { redr[tid >> 6] = pr; redi[tid >> 6] = pi; }
  __syncthreads();
  pr = redr[0] + redr[1] + redr[2] + redr[3];
  pi = redi[0] + redi[1] + redi[2] + redi[3];
}

// ---------------- 2-row row kernel ----------------
// Each block processes rows (2*bid, 2*bid+1). FFT twiddles, perm[] and beta[] are
// row-independent -> computed/loaded once per block. Barriers per row: 13/2 = 6.5
// (was 11). launch_bounds(256,2) -> 128 VGPRs (R1 lesson: size the register budget
// to the live state; peak live here ~90, so no spill at 128, but 64 would spill).
__global__ __launch_bounds__(256, 2) void urnn_row2(const _Float16* __restrict__ up16,
                                                    const float* __restrict__ hxr,
                                                    const float* __restrict__ hxi,
                                                    const float* __restrict__ beta,
                                                    const int* __restrict__ perm,
                                                    float* __restrict__ out,
                                                    int row0, long out_size_l, int omode) {
  __shared__ __half2 sA[2][HID], sB[2][HID];
  __shared__ float redr[16], redi[16];

  int tid = threadIdx.x;
  int rb = blockIdx.x * 2;
  int b0 = row0 + rb;
  const _Float16* up0 = up16 + (size_t)rb * FIVEH;

  // ---- phase 1: v = d1 * hx ; FFT head ----
#pragma unroll
  for (int r = 0; r < 2; ++r) {
    const _Float16* up = up0 + (size_t)r * FIVEH;
    float2 v[8];
#pragma unroll
    for (int e = 0; e < 8; ++e) {
      int k = tid + (e << 8);
      float sv, cv; __sincosf((float)up[k], &sv, &cv);
      float hr = hxr[(size_t)(b0 + r) * HID + k];
      float hi = hxi[(size_t)(b0 + r) * HID + k];
      v[e].x = cv * hr - sv * hi; v[e].y = cv * hi + sv * hr;
    }
    fft_head(v, sA[r], tid, -1.f);
  }
  __syncthreads();
  fft_mid2<8>(sA, sB, tid, -1.f);   __syncthreads();
  fft_mid2<32>(sB, sA, tid, -1.f);  __syncthreads();
  fft_mid2<128>(sA, sB, tid, -1.f); __syncthreads();

  // ---- FFT tail + Householder 1 (per-row; reduce barrier inside) ----
  {
    TailTw w = tail_tw(tid, -1.f);
#pragma unroll
    for (int r = 0; r < 2; ++r) {
      const _Float16* up = up0 + (size_t)r * FIVEH;
      float2 hreg[8];
      fft_tail_row(sB[r], hreg, tid, -1.f, w);
      float cc[8], ss[8];
      float pr = 0.f, pi = 0.f;
#pragma unroll
      for (int e = 0; e < 8; ++e) {
        float sv, cv; __sincosf((float)up[3 * HID + tid + (e << 8)], &sv, &cv);
        cc[e] = cv; ss[e] = sv;
        pr += cv * hreg[e].x + sv * hreg[e].y;
        pi += cv * hreg[e].y - sv * hreg[e].x;
      }
      block_reduce2(pr, pi, redr + 4 * r, redi + 4 * r, tid);
#pragma unroll
      for (int e = 0; e < 8; ++e) {
        int k = tid + (e << 8);
        h2st(sA[r], k, hreg[e].x - 2.f * (cc[e] * pr - ss[e] * pi),
                       hreg[e].y - 2.f * (cc[e] * pi + ss[e] * pr));
      }
    }
  }
  __syncthreads();

  // ---- permute + d2 * invN ; IFFT head ----
  {
    int pk[8];
#pragma unroll
    for (int e = 0; e < 8; ++e) pk[e] = perm[tid + (e << 8)];
    const float invN = 1.0f / (float)HID;
#pragma unroll
    for (int r = 0; r < 2; ++r) {
      const _Float16* up = up0 + (size_t)r * FIVEH;
      float2 v[8];
#pragma unroll
      for (int e = 0; e < 8; ++e) {
        int k = tid + (e << 8);
        float sv, cv; __sincosf((float)up[HID + k], &sv, &cv);
        float2 hh = h2ld(sA[r], pk[e]);
        v[e].x = (cv * hh.x - sv * hh.y) * invN;
        v[e].y = (cv * hh.y + sv * hh.x) * invN;
      }
      fft_head(v, sB[r], tid, 1.f);
    }
  }
  __syncthreads();
  fft_mid2<8>(sB, sA, tid, 1.f);   __syncthreads();
  fft_mid2<32>(sA, sB, tid, 1.f);  __syncthreads();
  fft_mid2<128>(sB, sA, tid, 1.f); __syncthreads();

  // ---- IFFT tail + Householder 2 + d3 + ModReLU + store (per-row) ----
  {
    TailTw w = tail_tw(tid, 1.f);
#pragma unroll
    for (int r = 0; r < 2; ++r) {
      const _Float16* up = up0 + (size_t)r * FIVEH;
      long b = b0 + r;
      float2 hreg[8];
      fft_tail_row(sA[r], hreg, tid, 1.f, w);
      float cc[8], ss[8];
      float pr = 0.f, pi = 0.f;
#pragma unroll
      for (int e = 0; e < 8; ++e) {
        float sv, cv; __sincosf((float)up[4 * HID + tid + (e << 8)], &sv, &cv);
        cc[e] = cv; ss[e] = sv;
        pr += cv * hreg[e].x + sv * hreg[e].y;
        pi += cv * hreg[e].y - sv * hreg[e].x;
      }
      block_reduce2(pr, pi, redr + 8 + 4 * r, redi + 8 + 4 * r, tid);
#pragma unroll
      for (int e = 0; e < 8; ++e) {
        int k = tid + (e << 8);
        float hr = hreg[e].x - 2.f * (cc[e] * pr - ss[e] * pi);
        float hi = hreg[e].y - 2.f * (cc[e] * pi + ss[e] * pr);
        float s3, c3; __sincosf((float)up[2 * HID + k], &s3, &c3);
        float zr = c3 * hr - s3 * hi;
        float zi = c3 * hi + s3 * hr;
        float mag = sqrtf(zr * zr + zi * zi);
        float nm = mag + beta[k];
        nm = nm > 0.f ? nm : 0.f;
        float orr, oii;
        if (mag > 0.f) { float sc = nm / mag; orr = zr * sc; oii = zi * sc; }
        else { orr = nm; oii = 0.f; }
        long m = b * HID + k;
        if (omode == 1) {
          const long half = (long)BATCH * HID;
          if (half + m < out_size_l) { out[m] = orr; out[half + m] = oii; }
        } else if (omode == 0) {
          if (2 * m + 1 < out_size_l) {
            float2 o; o.x = orr; o.y = oii;
            *(float2*)(out + 2 * m) = o;
          }
        } else {
          if (m < out_size_l) out[m] = orr;
        }
      }
    }
  }
}

// omode: 0 interleaved, 1 planar, 2 real-only. (fallback single-row pipeline)
#define ROW_PIPELINE(UP)                                                        \
  float2 hreg[8];                                                               \
  {                                                                             \
    float2 v[8];                                                                \
    _Pragma("unroll") for (int e = 0; e < 8; ++e) {                             \
      int k = tid + (e << 8);                                                   \
      float sv, cv; __sincosf(UP(e, 0), &sv, &cv);                              \
      float hr = hxr[(size_t)b * HID + k];                                      \
      float hi = hxi[(size_t)b * HID + k];                                      \
      v[e].x = cv * hr - sv * hi; v[e].y = cv * hi + sv * hr;                   \
    }                                                                           \
    fft_head(v, sA, tid, -1.f);                                                 \
  }                                                                             \
  __syncthreads();                                                              \
  fft_mid<8>(sA, sB, tid, -1.f);   __syncthreads();                             \
  fft_mid<32>(sB, sA, tid, -1.f);  __syncthreads();                             \
  fft_mid<128>(sA, sB, tid, -1.f); __syncthreads();                             \
  fft_tail(sB, hreg, tid, -1.f);                                                \
  float cc[8], ss[8];                                                           \
  {                                                                             \
    float pr = 0.f, pi = 0.f;                                                   \
    _Pragma("unroll") for (int e = 0; e < 8; ++e) {                             \
      float sv, cv; __sincosf(UP(e, 3), &sv, &cv);                              \
      cc[e] = cv; ss[e] = sv;                                                   \
      pr += cv * hreg[e].x + sv * hreg[e].y;                                    \
      pi += cv * hreg[e].y - sv * hreg[e].x;                                    \
    }                                                                           \
    block_reduce2(pr, pi, redr, redi, tid);                                     \
    _Pragma("unroll") for (int e = 0; e < 8; ++e) {                             \
      int k = tid + (e << 8);                                                   \
      h2st(sA, k, hreg[e].x - 2.f * (cc[e] * pr - ss[e] * pi),                  \
                  hreg[e].y - 2.f * (cc[e] * pi + ss[e] * pr));                 \
    }                                                                           \
  }                                                                             \
  __syncthreads();                                                              \
  {                                                                             \
    const float invN = 1.0f / (float)HID;                                       \
    float2 v[8];                                                                \
    _Pragma("unroll") for (int e = 0; e < 8; ++e) {                             \
      int k = tid + (e << 8);                                                   \
      float sv, cv; __sincosf(UP(e, 1), &sv, &cv);                              \
      float2 hh = h2ld(sA, perm[k]);                                            \
      v[e].x = (cv * hh.x - sv * hh.y) * invN;                                  \
      v[e].y = (cv * hh.y + sv * hh.x) * invN;                                  \
    }                                                                           \
    fft_head(v, sB, tid, 1.f);                                                  \
  }                                                                             \
  __syncthreads();                                                              \
  fft_mid<8>(sB, sA, tid, 1.f);   __syncthreads();                              \
  fft_mid<32>(sA, sB, tid, 1.f);  __syncthreads();                              \
  fft_mid<128>(sB, sA, tid, 1.f); __syncthreads();                              \
  fft_tail(sA, hreg, tid, 1.f);                                                 \
  float prj_r, prj_i;                                                           \
  {                                                                             \
    float pr = 0.f, pi = 0.f;                                                   \
    _Pragma("unroll") for (int e = 0; e < 8; ++e) {                             \
      float sv, cv; __sincosf(UP(e, 4), &sv, &cv);                              \
      cc[e] = cv; ss[e] = sv;                                                   \
      pr += cv * hreg[e].x + sv * hreg[e].y;                                    \
      pi += cv * hreg[e].y - sv * hreg[e].x;                                    \
    }                                                                           \
    block_reduce2(pr, pi, redr + 4, redi + 4, tid);                             \
    prj_r = pr; prj_i = pi;                                                     \
  }                                                                             \
  _Pragma("unroll") for (int e = 0; e < 8; ++e) {                               \
    int k = tid + (e << 8);                                                     \
    float hr = hreg[e].x - 2.f * (cc[e] * prj_r - ss[e] * prj_i);               \
    float hi = hreg[e].y - 2.f * (cc[e] * prj_i + ss[e] * prj_r);               \
    float s3, c3; __sincosf(UP(e, 2), &s3, &c3);                                \
    float zr = c3 * hr - s3 * hi;                                               \
    float zi = c3 * hi + s3 * hr;                                               \
    float mag = sqrtf(zr * zr + zi * zi);                                       \
    float nm = mag + beta[k];                                                   \
    nm = nm > 0.f ? nm : 0.f;                                                   \
    float orr, oii;                                                             \
    if (mag > 0.f) { float sc = nm / mag; orr = zr * sc; oii = zi * sc; }       \
    else { orr = nm; oii = 0.f; }                                               \
    long m = (long)b * HID + k;                                                 \
    if (omode == 1) {                                                           \
      const long half = (long)BATCH * HID;                                      \
      if (half + m < out_size_l) { out[m] = orr; out[half + m] = oii; }         \
    } else if (omode == 0) {                                                    \
      if (2 * m + 1 < out_size_l) {                                             \
        float2 o; o.x = orr; o.y = oii;                                         \
        *(float2*)(out + 2 * m) = o;                                            \
      }                                                                         \
    } else {                                                                    \
      if (m < out_size_l) out[m] = orr;                                         \
    }                                                                           \
  }

// ---------------- ws-free fused fallback (f32-exact per-thread GEMM) ------------------
__global__ __launch_bounds__(256) void urnn_fused(const float* __restrict__ A,
                                                  const float* __restrict__ W,
                                                  const float* __restrict__ bias,
                                                  const float* __restrict__ hxr,
                                                  const float* __restrict__ hxi,
                                                  const float* __restrict__ beta,
                                                  const int* __restrict__ perm,
                                                  float* __restrict__ out,
                                                  long out_size_l, int omode) {
  __shared__ __half2 sA[HID], sB[HID];
  __shared__ float redr[8], redi[8];
  __shared__ float4 xs4[INP / 4];

  int tid = threadIdx.x;
  int b = blockIdx.x;

  if (tid < INP / 4) xs4[tid] = ((const float4*)(A + (size_t)b * INP))[tid];
  __syncthreads();

  float upreg[40];
#pragma unroll
  for (int se = 0; se < 40; ++se) {
    int n = ((se >> 3) << 11) + ((se & 7) << 8) + tid;
    upreg[se] = bias[n];
  }
  for (int kb = 0; kb < 4; ++kb) {
    float4 xv[8];
#pragma unroll
    for (int j = 0; j < 8; ++j) xv[j] = xs4[kb * 8 + j];
#pragma unroll
    for (int se = 0; se < 40; ++se) {
      int n = ((se >> 3) << 11) + ((se & 7) << 8) + tid;
      const float4* wr = (const float4*)(W + (size_t)n * INP + (kb << 5));
      float a = 0.f;
#pragma unroll
      for (int j = 0; j < 8; ++j) {
        float4 wv = wr[j];
        a += xv[j].x * wv.x + xv[j].y * wv.y + xv[j].z * wv.z + xv[j].w * wv.w;
      }
      upreg[se] += a;
    }
  }
#define UPR(e, s) (upreg[(s) * 8 + (e)])
  ROW_PIPELINE(UPR)
#undef UPR
}

extern "C" void kernel_launch(void* const* d_in, const int* in_sizes, int n_in,
                              void* d_out, int out_size, void* d_ws, size_t ws_size,
                              hipStream_t stream) {
  const float* input   = (const float*)d_in[0];
  const float* hx_real = (const float*)d_in[1];
  const float* hx_imag = (const float*)d_in[2];
  const float* W       = (const float*)d_in[3];
  const float* bvec    = (const float*)d_in[4];
  const float* beta    = (const float*)d_in[5];
  const int*   perm    = (const int*)d_in[6];

  int omode;
  if (out_size == BATCH * HID) omode = 2;
  else if (out_size == 2 * BATCH * HID) omode = 1;
  else omode = 0;

  const size_t rowbytes = (size_t)FIVEH * sizeof(_Float16);
  long chunk = (long)(ws_size / rowbytes);
  if (chunk > BATCH) chunk = BATCH;
  chunk &= ~127L;

  if (chunk >= 128) {
    _Float16* up16 = (_Float16*)d_ws;
    for (long row0 = 0; row0 < BATCH; row0 += chunk) {
      int rows = (int)((row0 + chunk <= BATCH) ? chunk : (BATCH - row0));
      dim3 g(FIVEH / 128, rows / 128);
      gemm_up<<<g, 256, 0, stream>>>(input, W, bvec, up16, (int)row0, rows);
      urnn_row2<<<rows / 2, 256, 0, stream>>>(up16, hx_real, hx_imag, beta, perm,
                                              (float*)d_out, (int)row0, (long)out_size, omode);
    }
  } else {
    urnn_fused<<<BATCH, 256, 0, stream>>>(input, W, bvec, hx_real, hx_imag, beta, perm,
                                          (float*)d_out, (long)out_size, omode);
  }
}

// Round 4
// 145.565 us; speedup vs baseline: 1.0484x; 1.0484x over previous
//
#include <hip/hip_runtime.h>
#include <hip/hip_fp16.h>

#define HID 2048
#define FIVEH 10240
#define INP 128
#define BATCH 2048

typedef _Float16 half8 __attribute__((ext_vector_type(8)));
typedef float f32x4 __attribute__((ext_vector_type(4)));

// load 8 consecutive f32, convert to half8 in-register
__device__ __forceinline__ half8 cvt8(const float* p) {
  float4 a = *(const float4*)p;
  float4 b = *(const float4*)(p + 4);
  half8 h;
  h[0] = (_Float16)a.x; h[1] = (_Float16)a.y; h[2] = (_Float16)a.z; h[3] = (_Float16)a.w;
  h[4] = (_Float16)b.x; h[5] = (_Float16)b.y; h[6] = (_Float16)b.z; h[7] = (_Float16)b.w;
  return h;
}

// ---------------- GEMM v3 (unchanged, verified): LDS-staged W, transposed epilogue ----
#define WSTRIDE 136
__global__ __launch_bounds__(256) void gemm_up(const float* __restrict__ A,
                                               const float* __restrict__ W,
                                               const float* __restrict__ bias,
                                               _Float16* __restrict__ up16,
                                               int row0, int nrows) {
  __shared__ _Float16 Ws[128 * WSTRIDE];
  int tid = threadIdx.x, wave = tid >> 6, lane = tid & 63;
  int bx = blockIdx.x;
  int by = blockIdx.y;
  int nl = lane & 15, quad = lane >> 4;

  {
    const float* src = W + (size_t)(bx * 128) * INP;
#pragma unroll
    for (int it = 0; it < 8; ++it) {
      int n = (it * 256 + tid) * 8;
      int col = n >> 7, k = n & 127;
      *(half8*)(Ws + col * WSTRIDE + k) = cvt8(src + n);
    }
  }

  half8 af[2][4];
  int rowbase = row0 + by * 128 + wave * 32;
#pragma unroll
  for (int mt = 0; mt < 2; ++mt) {
    const float* ar = A + (size_t)(rowbase + mt * 16 + nl) * INP + quad * 8;
#pragma unroll
    for (int ks = 0; ks < 4; ++ks) af[mt][ks] = cvt8(ar + ks * 32);
  }
  __syncthreads();

  f32x4 acc[2][8];
#pragma unroll
  for (int nt = 0; nt < 8; ++nt) {
    half8 bf[4];
#pragma unroll
    for (int ks = 0; ks < 4; ++ks)
      bf[ks] = *(const half8*)(Ws + (nt * 16 + nl) * WSTRIDE + quad * 8 + ks * 32);
#pragma unroll
    for (int mt = 0; mt < 2; ++mt) {
      f32x4 a = {0.f, 0.f, 0.f, 0.f};
#pragma unroll
      for (int ks = 0; ks < 4; ++ks)
        a = __builtin_amdgcn_mfma_f32_16x16x32_f16(af[mt][ks], bf[ks], a, 0, 0, 0);
      acc[mt][nt] = a;
    }
  }
  __syncthreads();

#pragma unroll
  for (int nt = 0; nt < 8; ++nt) {
    float bv = bias[bx * 128 + nt * 16 + nl];
#pragma unroll
    for (int mt = 0; mt < 2; ++mt) {
      int rl = wave * 32 + mt * 16 + quad * 4;
#pragma unroll
      for (int r = 0; r < 4; ++r)
        Ws[(rl + r) * WSTRIDE + nt * 16 + nl] = (_Float16)(acc[mt][nt][r] + bv);
    }
  }
  __syncthreads();

#pragma unroll
  for (int it = 0; it < 8; ++it) {
    int v = it * 256 + tid;
    int r = v >> 4, c8 = (v & 15) * 8;
    *(half8*)(up16 + (size_t)(by * 128 + r) * FIVEH + bx * 128 + c8) =
        *(const half8*)(Ws + r * WSTRIDE + c8);
  }
}

// ---------------- f32 complex helper ----------------
__device__ __forceinline__ float2 cmulcs(float2 a, float c, float s) {
  float2 r; r.x = a.x * c - a.y * s; r.y = a.x * s + a.y * c; return r;  // a*(c+is)
}

// ---------------- radix-8 Stockham FFT, f32 LDS (2048 = 8*8*8*4) ----------------
// Convention (matches verified radix-4 code): o_j = sum_m y_m e^{i*sgn*2pi*jm/8}.
// Unit-vector checked: y=d0 -> all 1; y=d1 -> w^j; y=d2 -> (i*sgn)^j.
__device__ __forceinline__ void dft8(const float2 y[8], float2 o[8], float sgn) {
  const float R2 = 0.70710678118654752f;
  // even 4-pt DFT of y0,y2,y4,y6
  float ta0r = y[0].x + y[4].x, ta0i = y[0].y + y[4].y;
  float ta1r = y[0].x - y[4].x, ta1i = y[0].y - y[4].y;
  float ta2r = y[2].x + y[6].x, ta2i = y[2].y + y[6].y;
  float ta3r = y[2].x - y[6].x, ta3i = y[2].y - y[6].y;
  float E0r = ta0r + ta2r, E0i = ta0i + ta2i;
  float E2r = ta0r - ta2r, E2i = ta0i - ta2i;
  float E1r = ta1r - sgn * ta3i, E1i = ta1i + sgn * ta3r;
  float E3r = ta1r + sgn * ta3i, E3i = ta1i - sgn * ta3r;
  // odd 4-pt DFT of y1,y3,y5,y7
  float tb0r = y[1].x + y[5].x, tb0i = y[1].y + y[5].y;
  float tb1r = y[1].x - y[5].x, tb1i = y[1].y - y[5].y;
  float tb2r = y[3].x + y[7].x, tb2i = y[3].y + y[7].y;
  float tb3r = y[3].x - y[7].x, tb3i = y[3].y - y[7].y;
  float O0r = tb0r + tb2r, O0i = tb0i + tb2i;
  float O2r = tb0r - tb2r, O2i = tb0i - tb2i;
  float O1r = tb1r - sgn * tb3i, O1i = tb1i + sgn * tb3r;
  float O3r = tb1r + sgn * tb3i, O3i = tb1i - sgn * tb3r;
  // rotate odd outputs by w^j, w = e^{i*sgn*pi/4}
  float p1r = R2 * (O1r - sgn * O1i), p1i = R2 * (O1i + sgn * O1r);
  float p2r = -sgn * O2i,             p2i = sgn * O2r;
  float p3r = -R2 * (O3r + sgn * O3i), p3i = R2 * (sgn * O3r - O3i);
  o[0].x = E0r + O0r; o[0].y = E0i + O0i;
  o[4].x = E0r - O0r; o[4].y = E0i - O0i;
  o[1].x = E1r + p1r; o[1].y = E1i + p1i;
  o[5].x = E1r - p1r; o[5].y = E1i - p1i;
  o[2].x = E2r + p2r; o[2].y = E2i + p2i;
  o[6].x = E2r - p2r; o[6].y = E2i - p2i;
  o[3].x = E3r + p3r; o[3].y = E3i + p3i;
  o[7].x = E3r - p3r; o[7].y = E3i - p3i;
}

// HEAD = radix-8 pass, L=1 (k=0, unit twiddles). Input v[m] = point (tid+256m)
// already in registers; writes contiguous dst[8*tid + j].
__device__ __forceinline__ void fft8_head(const float2 v[8], float2* dst, int tid, float sgn) {
  float2 o[8];
  dft8(v, o, sgn);
  float2* base = dst + (tid << 3);
#pragma unroll
  for (int j = 0; j < 8; ++j) base[j] = o[j];
}

// radix-8 Stockham pass, L in {8,64}: reads src[tid+256m] (coalesced per lane),
// twiddle w^m = e^{i*sgn*pi*k*m/(4L)} (1 sincos + 6 cmults), 8-pt DFT,
// writes dst[8(tid-k)+k+j*L].
template <int L>
__device__ __forceinline__ void fft8_pass(const float2* __restrict__ src,
                                          float2* __restrict__ dst, int tid, float sgn) {
  const int k = tid & (L - 1);
  float s1, c1;
  __sincosf(sgn * (0.78539816339744831f / (float)L) * (float)k, &s1, &c1);  // pi/(4L)*k
  float c2 = c1 * c1 - s1 * s1,  s2 = 2.f * c1 * s1;
  float c3 = c2 * c1 - s2 * s1,  s3 = c2 * s1 + s2 * c1;
  float c4 = c2 * c2 - s2 * s2,  s4 = 2.f * c2 * s2;
  float c5 = c4 * c1 - s4 * s1,  s5 = c4 * s1 + s4 * c1;
  float c6 = c4 * c2 - s4 * s2,  s6 = c4 * s2 + s4 * c2;
  float c7 = c4 * c3 - s4 * s3,  s7 = c4 * s3 + s4 * c3;
  float2 y[8];
  y[0] = src[tid];
  y[1] = cmulcs(src[tid + 256],  c1, s1);
  y[2] = cmulcs(src[tid + 512],  c2, s2);
  y[3] = cmulcs(src[tid + 768],  c3, s3);
  y[4] = cmulcs(src[tid + 1024], c4, s4);
  y[5] = cmulcs(src[tid + 1280], c5, s5);
  y[6] = cmulcs(src[tid + 1536], c6, s6);
  y[7] = cmulcs(src[tid + 1792], c7, s7);
  float2 o[8];
  dft8(y, o, sgn);
  const int base = ((tid - k) << 3) + k;
#pragma unroll
  for (int j = 0; j < 8; ++j) dst[base + j * L] = o[j];
}

// TAIL: radix-4 pass L=512 (verified math, now f32) straight into registers;
// h[e] = point (tid + 256e).
__device__ __forceinline__ void fft_tail_f(const float2* __restrict__ src, float2 h[8],
                                           int tid, float sgn) {
#pragma unroll
  for (int t = 0; t < 2; ++t) {
    int i = tid + (t << 8);  // i in [0,512), k = i, base4 = i
    float s1, c1;
    __sincosf(sgn * (1.5707963267948966f / 512.f) * (float)i, &s1, &c1);
    float c2 = c1 * c1 - s1 * s1, s2 = 2.f * c1 * s1;
    float c3 = c1 * c2 - s1 * s2, s3 = c1 * s2 + s1 * c2;
    float2 x0 = src[i], x1 = src[i + 512], x2 = src[i + 1024], x3 = src[i + 1536];
    float y1r = x1.x * c1 - x1.y * s1, y1i = x1.x * s1 + x1.y * c1;
    float y2r = x2.x * c2 - x2.y * s2, y2i = x2.x * s2 + x2.y * c2;
    float y3r = x3.x * c3 - x3.y * s3, y3i = x3.x * s3 + x3.y * c3;
    float t0r = x0.x + y2r, t0i = x0.y + y2i;
    float t1r = x0.x - y2r, t1i = x0.y - y2i;
    float t2r = y1r + y3r, t2i = y1i + y3i;
    float t3r = y1r - y3r, t3i = y1i - y3i;
    h[t].x     = t0r + t2r;       h[t].y     = t0i + t2i;
    h[t + 4].x = t0r - t2r;       h[t + 4].y = t0i - t2i;
    h[t + 2].x = t1r - sgn * t3i; h[t + 2].y = t1i + sgn * t3r;
    h[t + 6].x = t1r + sgn * t3i; h[t + 6].y = t1i - sgn * t3r;
  }
}

// wave shfl reduce + tiny LDS combine. Caller provides a PRIVATE red buffer per call
// site, so no trailing barrier is needed (single sync per reduction).
__device__ __forceinline__ void block_reduce2(float& pr, float& pi,
                                              float* redr, float* redi, int tid) {
  for (int off = 32; off > 0; off >>= 1) {
    pr += __shfl_down(pr, off, 64);
    pi += __shfl_down(pi, off, 64);
  }
  if ((tid & 63) == 0) { redr[tid >> 6] = pr; redi[tid >> 6] = pi; }
  __syncthreads();
  pr = redr[0] + redr[1] + redr[2] + redr[3];
  pi = redi[0] + redi[1] + redi[2] + redi[3];
}

// omode: 0 interleaved, 1 planar, 2 real-only. invN folded at the permute step.
// Pipeline: 9 barriers, 7R+7W f32 LDS rounds (was 11 / 9R+9W with f16 cvt churn).
//   head(d1*hx,r8 L=1)->sA | p8 sA->sB | p64 sB->sA | tail(sA)->regs | HH1(reduce)
//   -> write sB | perm+d2 gather sB -> head(r8)->sA | p8 sA->sB | p64 sB->sA |
//   tail(sA)->regs | HH2(reduce) + d3 + modrelu -> out
#define ROW_PIPELINE(UP)                                                        \
  float2 hreg[8];                                                               \
  {                                                                             \
    float2 v[8];                                                                \
    _Pragma("unroll") for (int e = 0; e < 8; ++e) {                             \
      int k = tid + (e << 8);                                                   \
      float sv, cv; __sincosf(UP(e, 0), &sv, &cv);                              \
      float hr = hxr[(size_t)b * HID + k];                                      \
      float hi = hxi[(size_t)b * HID + k];                                      \
      v[e].x = cv * hr - sv * hi; v[e].y = cv * hi + sv * hr;                   \
    }                                                                           \
    fft8_head(v, sA, tid, -1.f);                                                \
  }                                                                             \
  __syncthreads();                                                              \
  fft8_pass<8>(sA, sB, tid, -1.f);  __syncthreads();                            \
  fft8_pass<64>(sB, sA, tid, -1.f); __syncthreads();                            \
  fft_tail_f(sA, hreg, tid, -1.f);                                              \
  float cc[8], ss[8];                                                           \
  {                                                                             \
    float pr = 0.f, pi = 0.f;                                                   \
    _Pragma("unroll") for (int e = 0; e < 8; ++e) {                             \
      float sv, cv; __sincosf(UP(e, 3), &sv, &cv);                              \
      cc[e] = cv; ss[e] = sv;                                                   \
      pr += cv * hreg[e].x + sv * hreg[e].y;                                    \
      pi += cv * hreg[e].y - sv * hreg[e].x;                                    \
    }                                                                           \
    block_reduce2(pr, pi, redr, redi, tid);                                     \
    _Pragma("unroll") for (int e = 0; e < 8; ++e) {                             \
      int k = tid + (e << 8);                                                   \
      sB[k].x = hreg[e].x - 2.f * (cc[e] * pr - ss[e] * pi);                    \
      sB[k].y = hreg[e].y - 2.f * (cc[e] * pi + ss[e] * pr);                    \
    }                                                                           \
  }                                                                             \
  __syncthreads();                                                              \
  {                                                                             \
    const float invN = 1.0f / (float)HID;                                       \
    float2 v[8];                                                                \
    _Pragma("unroll") for (int e = 0; e < 8; ++e) {                             \
      int k = tid + (e << 8);                                                   \
      float sv, cv; __sincosf(UP(e, 1), &sv, &cv);                              \
      float2 hh = sB[perm[k]];                                                  \
      v[e].x = (cv * hh.x - sv * hh.y) * invN;                                  \
      v[e].y = (cv * hh.y + sv * hh.x) * invN;                                  \
    }                                                                           \
    fft8_head(v, sA, tid, 1.f);                                                 \
  }                                                                             \
  __syncthreads();                                                              \
  fft8_pass<8>(sA, sB, tid, 1.f);  __syncthreads();                             \
  fft8_pass<64>(sB, sA, tid, 1.f); __syncthreads();                             \
  fft_tail_f(sA, hreg, tid, 1.f);                                               \
  float prj_r, prj_i;                                                           \
  {                                                                             \
    float pr = 0.f, pi = 0.f;                                                   \
    _Pragma("unroll") for (int e = 0; e < 8; ++e) {                             \
      float sv, cv; __sincosf(UP(e, 4), &sv, &cv);                              \
      cc[e] = cv; ss[e] = sv;                                                   \
      pr += cv * hreg[e].x + sv * hreg[e].y;                                    \
      pi += cv * hreg[e].y - sv * hreg[e].x;                                    \
    }                                                                           \
    block_reduce2(pr, pi, redr + 4, redi + 4, tid);                             \
    prj_r = pr; prj_i = pi;                                                     \
  }                                                                             \
  _Pragma("unroll") for (int e = 0; e < 8; ++e) {                               \
    int k = tid + (e << 8);                                                     \
    float hr = hreg[e].x - 2.f * (cc[e] * prj_r - ss[e] * prj_i);               \
    float hi = hreg[e].y - 2.f * (cc[e] * prj_i + ss[e] * prj_r);               \
    float s3, c3; __sincosf(UP(e, 2), &s3, &c3);                                \
    float zr = c3 * hr - s3 * hi;                                               \
    float zi = c3 * hi + s3 * hr;                                               \
    float mag = sqrtf(zr * zr + zi * zi);                                       \
    float nm = mag + beta[k];                                                   \
    nm = nm > 0.f ? nm : 0.f;                                                   \
    float orr, oii;                                                             \
    if (mag > 0.f) { float sc = nm / mag; orr = zr * sc; oii = zi * sc; }       \
    else { orr = nm; oii = 0.f; }                                               \
    long m = (long)b * HID + k;                                                 \
    if (omode == 1) {                                                           \
      const long half = (long)BATCH * HID;                                      \
      if (half + m < out_size_l) { out[m] = orr; out[half + m] = oii; }         \
    } else if (omode == 0) {                                                    \
      if (2 * m + 1 < out_size_l) {                                             \
        float2 o; o.x = orr; o.y = oii;                                         \
        *(float2*)(out + 2 * m) = o;                                            \
      }                                                                         \
    } else {                                                                    \
      if (m < out_size_l) out[m] = orr;                                         \
    }                                                                           \
  }

// ---------------- row kernel: 1 row/block (R3 2-row regressed: occupancy 23%) ----
// launch_bounds(256,4): 128-VGPR budget; live state peaks ~90 in tail+HH (R1
// lesson: (256,8)'s 32-VGPR cap spills this pipeline to scratch).
__global__ __launch_bounds__(256, 4) void urnn_row(const _Float16* __restrict__ up16,
                                                   const float* __restrict__ hxr,
                                                   const float* __restrict__ hxi,
                                                   const float* __restrict__ beta,
                                                   const int* __restrict__ perm,
                                                   float* __restrict__ out,
                                                   int row0, long out_size_l, int omode) {
  __shared__ float2 sA[HID], sB[HID];   // 32 KB f32 state: no cvt churn, 4 blocks/CU
  __shared__ float redr[8], redi[8];

  int tid = threadIdx.x;
  int b = row0 + blockIdx.x;
  const _Float16* uprow = up16 + (size_t)blockIdx.x * FIVEH;
#define UPG(e, s) ((float)uprow[(s) * HID + tid + ((e) << 8)])
  ROW_PIPELINE(UPG)
#undef UPG
}

// ---------------- ws-free fused fallback (f32-exact per-thread GEMM) ------------------
__global__ __launch_bounds__(256) void urnn_fused(const float* __restrict__ A,
                                                  const float* __restrict__ W,
                                                  const float* __restrict__ bias,
                                                  const float* __restrict__ hxr,
                                                  const float* __restrict__ hxi,
                                                  const float* __restrict__ beta,
                                                  const int* __restrict__ perm,
                                                  float* __restrict__ out,
                                                  long out_size_l, int omode) {
  __shared__ float2 sA[HID], sB[HID];
  __shared__ float redr[8], redi[8];
  __shared__ float4 xs4[INP / 4];

  int tid = threadIdx.x;
  int b = blockIdx.x;

  if (tid < INP / 4) xs4[tid] = ((const float4*)(A + (size_t)b * INP))[tid];
  __syncthreads();

  float upreg[40];
#pragma unroll
  for (int se = 0; se < 40; ++se) {
    int n = ((se >> 3) << 11) + ((se & 7) << 8) + tid;
    upreg[se] = bias[n];
  }
  for (int kb = 0; kb < 4; ++kb) {
    float4 xv[8];
#pragma unroll
    for (int j = 0; j < 8; ++j) xv[j] = xs4[kb * 8 + j];
#pragma unroll
    for (int se = 0; se < 40; ++se) {
      int n = ((se >> 3) << 11) + ((se & 7) << 8) + tid;
      const float4* wr = (const float4*)(W + (size_t)n * INP + (kb << 5));
      float a = 0.f;
#pragma unroll
      for (int j = 0; j < 8; ++j) {
        float4 wv = wr[j];
        a += xv[j].x * wv.x + xv[j].y * wv.y + xv[j].z * wv.z + xv[j].w * wv.w;
      }
      upreg[se] += a;
    }
  }
#define UPR(e, s) (upreg[(s) * 8 + (e)])
  ROW_PIPELINE(UPR)
#undef UPR
}

extern "C" void kernel_launch(void* const* d_in, const int* in_sizes, int n_in,
                              void* d_out, int out_size, void* d_ws, size_t ws_size,
                              hipStream_t stream) {
  const float* input   = (const float*)d_in[0];
  const float* hx_real = (const float*)d_in[1];
  const float* hx_imag = (const float*)d_in[2];
  const float* W       = (const float*)d_in[3];
  const float* bvec    = (const float*)d_in[4];
  const float* beta    = (const float*)d_in[5];
  const int*   perm    = (const int*)d_in[6];

  int omode;
  if (out_size == BATCH * HID) omode = 2;
  else if (out_size == 2 * BATCH * HID) omode = 1;
  else omode = 0;

  const size_t rowbytes = (size_t)FIVEH * sizeof(_Float16);
  long chunk = (long)(ws_size / rowbytes);
  if (chunk > BATCH) chunk = BATCH;
  chunk &= ~127L;

  if (chunk >= 128) {
    _Float16* up16 = (_Float16*)d_ws;
    for (long row0 = 0; row0 < BATCH; row0 += chunk) {
      int rows = (int)((row0 + chunk <= BATCH) ? chunk : (BATCH - row0));
      dim3 g(FIVEH / 128, rows / 128);
      gemm_up<<<g, 256, 0, stream>>>(input, W, bvec, up16, (int)row0, rows);
      urnn_row<<<rows, 256, 0, stream>>>(up16, hx_real, hx_imag, beta, perm,
                                         (float*)d_out, (int)row0, (long)out_size, omode);
    }
  } else {
    urnn_fused<<<BATCH, 256, 0, stream>>>(input, W, bvec, hx_real, hx_imag, beta, perm,
                                          (float*)d_out, (long)out_size, omode);
  }
}

// Round 5
// 144.960 us; speedup vs baseline: 1.0528x; 1.0042x over previous
//
#include <hip/hip_runtime.h>
#include <hip/hip_fp16.h>

#define HID 2048
#define FIVEH 10240
#define INP 128
#define BATCH 2048

// padded f32 LDS: phys(i) = i + (i>>4).  2048 -> 2176 float2 per buffer.
// Reads fold exactly: PHI(x + 16c) = PHI(x) + 17c  (256m -> +272m, 512m -> +544m,
// 64j -> +68j).  Kills the f32 layout's write conflicts (head 32-way -> 4-way,
// p8 8-way -> 4-way) while keeping all strided reads conflict-free.
#define NPAD 2176
#define PHI(i) ((i) + ((i) >> 4))

typedef _Float16 half8 __attribute__((ext_vector_type(8)));
typedef float f32x4 __attribute__((ext_vector_type(4)));

// load 8 consecutive f32, convert to half8 in-register
__device__ __forceinline__ half8 cvt8(const float* p) {
  float4 a = *(const float4*)p;
  float4 b = *(const float4*)(p + 4);
  half8 h;
  h[0] = (_Float16)a.x; h[1] = (_Float16)a.y; h[2] = (_Float16)a.z; h[3] = (_Float16)a.w;
  h[4] = (_Float16)b.x; h[5] = (_Float16)b.y; h[6] = (_Float16)b.z; h[7] = (_Float16)b.w;
  return h;
}

// ---------------- GEMM v3 (unchanged, verified): LDS-staged W, transposed epilogue ----
#define WSTRIDE 136
__global__ __launch_bounds__(256) void gemm_up(const float* __restrict__ A,
                                               const float* __restrict__ W,
                                               const float* __restrict__ bias,
                                               _Float16* __restrict__ up16,
                                               int row0, int nrows) {
  __shared__ _Float16 Ws[128 * WSTRIDE];
  int tid = threadIdx.x, wave = tid >> 6, lane = tid & 63;
  int bx = blockIdx.x;
  int by = blockIdx.y;
  int nl = lane & 15, quad = lane >> 4;

  {
    const float* src = W + (size_t)(bx * 128) * INP;
#pragma unroll
    for (int it = 0; it < 8; ++it) {
      int n = (it * 256 + tid) * 8;
      int col = n >> 7, k = n & 127;
      *(half8*)(Ws + col * WSTRIDE + k) = cvt8(src + n);
    }
  }

  half8 af[2][4];
  int rowbase = row0 + by * 128 + wave * 32;
#pragma unroll
  for (int mt = 0; mt < 2; ++mt) {
    const float* ar = A + (size_t)(rowbase + mt * 16 + nl) * INP + quad * 8;
#pragma unroll
    for (int ks = 0; ks < 4; ++ks) af[mt][ks] = cvt8(ar + ks * 32);
  }
  __syncthreads();

  f32x4 acc[2][8];
#pragma unroll
  for (int nt = 0; nt < 8; ++nt) {
    half8 bf[4];
#pragma unroll
    for (int ks = 0; ks < 4; ++ks)
      bf[ks] = *(const half8*)(Ws + (nt * 16 + nl) * WSTRIDE + quad * 8 + ks * 32);
#pragma unroll
    for (int mt = 0; mt < 2; ++mt) {
      f32x4 a = {0.f, 0.f, 0.f, 0.f};
#pragma unroll
      for (int ks = 0; ks < 4; ++ks)
        a = __builtin_amdgcn_mfma_f32_16x16x32_f16(af[mt][ks], bf[ks], a, 0, 0, 0);
      acc[mt][nt] = a;
    }
  }
  __syncthreads();

#pragma unroll
  for (int nt = 0; nt < 8; ++nt) {
    float bv = bias[bx * 128 + nt * 16 + nl];
#pragma unroll
    for (int mt = 0; mt < 2; ++mt) {
      int rl = wave * 32 + mt * 16 + quad * 4;
#pragma unroll
      for (int r = 0; r < 4; ++r)
        Ws[(rl + r) * WSTRIDE + nt * 16 + nl] = (_Float16)(acc[mt][nt][r] + bv);
    }
  }
  __syncthreads();

#pragma unroll
  for (int it = 0; it < 8; ++it) {
    int v = it * 256 + tid;
    int r = v >> 4, c8 = (v & 15) * 8;
    *(half8*)(up16 + (size_t)(by * 128 + r) * FIVEH + bx * 128 + c8) =
        *(const half8*)(Ws + r * WSTRIDE + c8);
  }
}

// ---------------- f32 complex helper ----------------
__device__ __forceinline__ float2 cmulcs(float2 a, float c, float s) {
  float2 r; r.x = a.x * c - a.y * s; r.y = a.x * s + a.y * c; return r;  // a*(c+is)
}

// ---------------- radix-8 Stockham FFT, padded f32 LDS (2048 = 8*8*8*4) ----------
// o_j = sum_m y_m e^{i*sgn*2pi*jm/8} (same convention as verified radix-4 code).
__device__ __forceinline__ void dft8(const float2 y[8], float2 o[8], float sgn) {
  const float R2 = 0.70710678118654752f;
  float ta0r = y[0].x + y[4].x, ta0i = y[0].y + y[4].y;
  float ta1r = y[0].x - y[4].x, ta1i = y[0].y - y[4].y;
  float ta2r = y[2].x + y[6].x, ta2i = y[2].y + y[6].y;
  float ta3r = y[2].x - y[6].x, ta3i = y[2].y - y[6].y;
  float E0r = ta0r + ta2r, E0i = ta0i + ta2i;
  float E2r = ta0r - ta2r, E2i = ta0i - ta2i;
  float E1r = ta1r - sgn * ta3i, E1i = ta1i + sgn * ta3r;
  float E3r = ta1r + sgn * ta3i, E3i = ta1i - sgn * ta3r;
  float tb0r = y[1].x + y[5].x, tb0i = y[1].y + y[5].y;
  float tb1r = y[1].x - y[5].x, tb1i = y[1].y - y[5].y;
  float tb2r = y[3].x + y[7].x, tb2i = y[3].y + y[7].y;
  float tb3r = y[3].x - y[7].x, tb3i = y[3].y - y[7].y;
  float O0r = tb0r + tb2r, O0i = tb0i + tb2i;
  float O2r = tb0r - tb2r, O2i = tb0i - tb2i;
  float O1r = tb1r - sgn * tb3i, O1i = tb1i + sgn * tb3r;
  float O3r = tb1r + sgn * tb3i, O3i = tb1i - sgn * tb3r;
  float p1r = R2 * (O1r - sgn * O1i), p1i = R2 * (O1i + sgn * O1r);
  float p2r = -sgn * O2i,             p2i = sgn * O2r;
  float p3r = -R2 * (O3r + sgn * O3i), p3i = R2 * (sgn * O3r - O3i);
  o[0].x = E0r + O0r; o[0].y = E0i + O0i;
  o[4].x = E0r - O0r; o[4].y = E0i - O0i;
  o[1].x = E1r + p1r; o[1].y = E1i + p1i;
  o[5].x = E1r - p1r; o[5].y = E1i - p1i;
  o[2].x = E2r + p2r; o[2].y = E2i + p2i;
  o[6].x = E2r - p2r; o[6].y = E2i - p2i;
  o[3].x = E3r + p3r; o[3].y = E3i + p3i;
  o[7].x = E3r - p3r; o[7].y = E3i - p3i;
}

// HEAD = radix-8 pass, L=1 (k=0, unit twiddles). Input v[m] = point (tid+256m).
// Writes logical [8t..8t+7] at phys PHI(8t+j) = 8t + j + (t>>1): contiguous 8,
// bank spread 4-way (was 32-way unpadded).
__device__ __forceinline__ void fft8_head(const float2 v[8], float2* dst, int tid, float sgn) {
  float2 o[8];
  dft8(v, o, sgn);
  float2* base = dst + (tid << 3) + (tid >> 1);
#pragma unroll
  for (int j = 0; j < 8; ++j) base[j] = o[j];
}

// radix-8 Stockham pass, L in {8,64}: reads phys PHI(tid)+272m (conflict-free,
// compile-time offsets), twiddle w^m = e^{i*sgn*pi*k*m/(4L)}, 8-pt DFT,
// writes phys PHI(8(tid-k)+k+jL) (<=4-way).
template <int L>
__device__ __forceinline__ void fft8_pass(const float2* __restrict__ src,
                                          float2* __restrict__ dst, int tid, float sgn) {
  const int k = tid & (L - 1);
  float s1, c1;
  __sincosf(sgn * (0.78539816339744831f / (float)L) * (float)k, &s1, &c1);  // pi/(4L)*k
  float c2 = c1 * c1 - s1 * s1,  s2 = 2.f * c1 * s1;
  float c3 = c2 * c1 - s2 * s1,  s3 = c2 * s1 + s2 * c1;
  float c4 = c2 * c2 - s2 * s2,  s4 = 2.f * c2 * s2;
  float c5 = c4 * c1 - s4 * s1,  s5 = c4 * s1 + s4 * c1;
  float c6 = c4 * c2 - s4 * s2,  s6 = c4 * s2 + s4 * c2;
  float c7 = c4 * c3 - s4 * s3,  s7 = c4 * s3 + s4 * c3;
  const int rb = tid + (tid >> 4);  // PHI(tid)
  float2 y[8];
  y[0] = src[rb];
  y[1] = cmulcs(src[rb + 272],  c1, s1);
  y[2] = cmulcs(src[rb + 544],  c2, s2);
  y[3] = cmulcs(src[rb + 816],  c3, s3);
  y[4] = cmulcs(src[rb + 1088], c4, s4);
  y[5] = cmulcs(src[rb + 1360], c5, s5);
  y[6] = cmulcs(src[rb + 1632], c6, s6);
  y[7] = cmulcs(src[rb + 1904], c7, s7);
  float2 o[8];
  dft8(y, o, sgn);
  const int base = ((tid - k) << 3) + k;
#pragma unroll
  for (int j = 0; j < 8; ++j) {
    int a = base + j * L;
    dst[a + (a >> 4)] = o[j];
  }
}

// TAIL: radix-4 pass L=512 straight into registers; h[e] = point (tid + 256e).
// Reads phys PHI(i)+544m (conflict-free).
__device__ __forceinline__ void fft_tail_f(const float2* __restrict__ src, float2 h[8],
                                           int tid, float sgn) {
#pragma unroll
  for (int t = 0; t < 2; ++t) {
    int i = tid + (t << 8);  // i in [0,512), k = i
    float s1, c1;
    __sincosf(sgn * (1.5707963267948966f / 512.f) * (float)i, &s1, &c1);
    float c2 = c1 * c1 - s1 * s1, s2 = 2.f * c1 * s1;
    float c3 = c1 * c2 - s1 * s2, s3 = c1 * s2 + s1 * c2;
    const int rb = i + (i >> 4);  // PHI(i)
    float2 x0 = src[rb], x1 = src[rb + 544], x2 = src[rb + 1088], x3 = src[rb + 1632];
    float y1r = x1.x * c1 - x1.y * s1, y1i = x1.x * s1 + x1.y * c1;
    float y2r = x2.x * c2 - x2.y * s2, y2i = x2.x * s2 + x2.y * c2;
    float y3r = x3.x * c3 - x3.y * s3, y3i = x3.x * s3 + x3.y * c3;
    float t0r = x0.x + y2r, t0i = x0.y + y2i;
    float t1r = x0.x - y2r, t1i = x0.y - y2i;
    float t2r = y1r + y3r, t2i = y1i + y3i;
    float t3r = y1r - y3r, t3i = y1i - y3i;
    h[t].x     = t0r + t2r;       h[t].y     = t0i + t2i;
    h[t + 4].x = t0r - t2r;       h[t + 4].y = t0i - t2i;
    h[t + 2].x = t1r - sgn * t3i; h[t + 2].y = t1i + sgn * t3r;
    h[t + 6].x = t1r + sgn * t3i; h[t + 6].y = t1i - sgn * t3r;
  }
}

// wave shfl reduce + tiny LDS combine. Caller provides a PRIVATE red buffer per call
// site, so no trailing barrier is needed (single sync per reduction).
__device__ __forceinline__ void block_reduce2(float& pr, float& pi,
                                              float* redr, float* redi, int tid) {
  for (int off = 32; off > 0; off >>= 1) {
    pr += __shfl_down(pr, off, 64);
    pi += __shfl_down(pi, off, 64);
  }
  if ((tid & 63) == 0) { redr[tid >> 6] = pr; redi[tid >> 6] = pi; }
  __syncthreads();
  pr = redr[0] + redr[1] + redr[2] + redr[3];
  pi = redi[0] + redi[1] + redi[2] + redi[3];
}

// omode: 0 interleaved, 1 planar, 2 real-only. invN folded at the permute step.
// Pipeline: 9 barriers, 7R+7W padded-f32 LDS rounds.
#define ROW_PIPELINE(UP)                                                        \
  float2 hreg[8];                                                               \
  {                                                                             \
    float2 v[8];                                                                \
    _Pragma("unroll") for (int e = 0; e < 8; ++e) {                             \
      int k = tid + (e << 8);                                                   \
      float sv, cv; __sincosf(UP(e, 0), &sv, &cv);                              \
      float hr = hxr[(size_t)b * HID + k];                                      \
      float hi = hxi[(size_t)b * HID + k];                                      \
      v[e].x = cv * hr - sv * hi; v[e].y = cv * hi + sv * hr;                   \
    }                                                                           \
    fft8_head(v, sA, tid, -1.f);                                                \
  }                                                                             \
  __syncthreads();                                                              \
  fft8_pass<8>(sA, sB, tid, -1.f);  __syncthreads();                            \
  fft8_pass<64>(sB, sA, tid, -1.f); __syncthreads();                            \
  fft_tail_f(sA, hreg, tid, -1.f);                                              \
  float cc[8], ss[8];                                                           \
  {                                                                             \
    float pr = 0.f, pi = 0.f;                                                   \
    _Pragma("unroll") for (int e = 0; e < 8; ++e) {                             \
      float sv, cv; __sincosf(UP(e, 3), &sv, &cv);                              \
      cc[e] = cv; ss[e] = sv;                                                   \
      pr += cv * hreg[e].x + sv * hreg[e].y;                                    \
      pi += cv * hreg[e].y - sv * hreg[e].x;                                    \
    }                                                                           \
    block_reduce2(pr, pi, redr, redi, tid);                                     \
    const int wb = tid + (tid >> 4);  /* PHI(tid); +272e per element */         \
    _Pragma("unroll") for (int e = 0; e < 8; ++e) {                             \
      sB[wb + 272 * e].x = hreg[e].x - 2.f * (cc[e] * pr - ss[e] * pi);         \
      sB[wb + 272 * e].y = hreg[e].y - 2.f * (cc[e] * pi + ss[e] * pr);         \
    }                                                                           \
  }                                                                             \
  __syncthreads();                                                              \
  {                                                                             \
    const float invN = 1.0f / (float)HID;                                       \
    float2 v[8];                                                                \
    _Pragma("unroll") for (int e = 0; e < 8; ++e) {                             \
      int k = tid + (e << 8);                                                   \
      float sv, cv; __sincosf(UP(e, 1), &sv, &cv);                              \
      int p = perm[k];                                                          \
      float2 hh = sB[p + (p >> 4)];                                             \
      v[e].x = (cv * hh.x - sv * hh.y) * invN;                                  \
      v[e].y = (cv * hh.y + sv * hh.x) * invN;                                  \
    }                                                                           \
    fft8_head(v, sA, tid, 1.f);                                                 \
  }                                                                             \
  __syncthreads();                                                              \
  fft8_pass<8>(sA, sB, tid, 1.f);  __syncthreads();                             \
  fft8_pass<64>(sB, sA, tid, 1.f); __syncthreads();                             \
  fft_tail_f(sA, hreg, tid, 1.f);                                               \
  float prj_r, prj_i;                                                           \
  {                                                                             \
    float pr = 0.f, pi = 0.f;                                                   \
    _Pragma("unroll") for (int e = 0; e < 8; ++e) {                             \
      float sv, cv; __sincosf(UP(e, 4), &sv, &cv);                              \
      cc[e] = cv; ss[e] = sv;                                                   \
      pr += cv * hreg[e].x + sv * hreg[e].y;                                    \
      pi += cv * hreg[e].y - sv * hreg[e].x;                                    \
    }                                                                           \
    block_reduce2(pr, pi, redr + 4, redi + 4, tid);                             \
    prj_r = pr; prj_i = pi;                                                     \
  }                                                                             \
  _Pragma("unroll") for (int e = 0; e < 8; ++e) {                               \
    int k = tid + (e << 8);                                                     \
    float hr = hreg[e].x - 2.f * (cc[e] * prj_r - ss[e] * prj_i);               \
    float hi = hreg[e].y - 2.f * (cc[e] * prj_i + ss[e] * prj_r);               \
    float s3, c3; __sincosf(UP(e, 2), &s3, &c3);                                \
    float zr = c3 * hr - s3 * hi;                                               \
    float zi = c3 * hi + s3 * hr;                                               \
    float mag = sqrtf(zr * zr + zi * zi);                                       \
    float nm = mag + beta[k];                                                   \
    nm = nm > 0.f ? nm : 0.f;                                                   \
    float orr, oii;                                                             \
    if (mag > 0.f) { float sc = nm / mag; orr = zr * sc; oii = zi * sc; }       \
    else { orr = nm; oii = 0.f; }                                               \
    long m = (long)b * HID + k;                                                 \
    if (omode == 1) {                                                           \
      const long half = (long)BATCH * HID;                                      \
      if (half + m < out_size_l) { out[m] = orr; out[half + m] = oii; }         \
    } else if (omode == 0) {                                                    \
      if (2 * m + 1 < out_size_l) {                                             \
        float2 o; o.x = orr; o.y = oii;                                         \
        *(float2*)(out + 2 * m) = o;                                            \
      }                                                                         \
    } else {                                                                    \
      if (m < out_size_l) out[m] = orr;                                         \
    }                                                                           \
  }

// ---------------- row kernel: 1 row/block, padded f32 LDS ----------------
// launch_bounds(256,4): 128-VGPR budget (R1: (256,8)'s 32-VGPR cap spills).
__global__ __launch_bounds__(256, 4) void urnn_row(const _Float16* __restrict__ up16,
                                                   const float* __restrict__ hxr,
                                                   const float* __restrict__ hxi,
                                                   const float* __restrict__ beta,
                                                   const int* __restrict__ perm,
                                                   float* __restrict__ out,
                                                   int row0, long out_size_l, int omode) {
  __shared__ float2 sA[NPAD], sB[NPAD];   // 34.8 KB padded f32 state, 4 blocks/CU
  __shared__ float redr[8], redi[8];

  int tid = threadIdx.x;
  int b = row0 + blockIdx.x;
  const _Float16* uprow = up16 + (size_t)blockIdx.x * FIVEH;
#define UPG(e, s) ((float)uprow[(s) * HID + tid + ((e) << 8)])
  ROW_PIPELINE(UPG)
#undef UPG
}

// ---------------- ws-free fused fallback (f32-exact per-thread GEMM) ------------------
__global__ __launch_bounds__(256) void urnn_fused(const float* __restrict__ A,
                                                  const float* __restrict__ W,
                                                  const float* __restrict__ bias,
                                                  const float* __restrict__ hxr,
                                                  const float* __restrict__ hxi,
                                                  const float* __restrict__ beta,
                                                  const int* __restrict__ perm,
                                                  float* __restrict__ out,
                                                  long out_size_l, int omode) {
  __shared__ float2 sA[NPAD], sB[NPAD];
  __shared__ float redr[8], redi[8];
  __shared__ float4 xs4[INP / 4];

  int tid = threadIdx.x;
  int b = blockIdx.x;

  if (tid < INP / 4) xs4[tid] = ((const float4*)(A + (size_t)b * INP))[tid];
  __syncthreads();

  float upreg[40];
#pragma unroll
  for (int se = 0; se < 40; ++se) {
    int n = ((se >> 3) << 11) + ((se & 7) << 8) + tid;
    upreg[se] = bias[n];
  }
  for (int kb = 0; kb < 4; ++kb) {
    float4 xv[8];
#pragma unroll
    for (int j = 0; j < 8; ++j) xv[j] = xs4[kb * 8 + j];
#pragma unroll
    for (int se = 0; se < 40; ++se) {
      int n = ((se >> 3) << 11) + ((se & 7) << 8) + tid;
      const float4* wr = (const float4*)(W + (size_t)n * INP + (kb << 5));
      float a = 0.f;
#pragma unroll
      for (int j = 0; j < 8; ++j) {
        float4 wv = wr[j];
        a += xv[j].x * wv.x + xv[j].y * wv.y + xv[j].z * wv.z + xv[j].w * wv.w;
      }
      upreg[se] += a;
    }
  }
#define UPR(e, s) (upreg[(s) * 8 + (e)])
  ROW_PIPELINE(UPR)
#undef UPR
}

extern "C" void kernel_launch(void* const* d_in, const int* in_sizes, int n_in,
                              void* d_out, int out_size, void* d_ws, size_t ws_size,
                              hipStream_t stream) {
  const float* input   = (const float*)d_in[0];
  const float* hx_real = (const float*)d_in[1];
  const float* hx_imag = (const float*)d_in[2];
  const float* W       = (const float*)d_in[3];
  const float* bvec    = (const float*)d_in[4];
  const float* beta    = (const float*)d_in[5];
  const int*   perm    = (const int*)d_in[6];

  int omode;
  if (out_size == BATCH * HID) omode = 2;
  else if (out_size == 2 * BATCH * HID) omode = 1;
  else omode = 0;

  const size_t rowbytes = (size_t)FIVEH * sizeof(_Float16);
  long chunk = (long)(ws_size / rowbytes);
  if (chunk > BATCH) chunk = BATCH;
  chunk &= ~127L;

  if (chunk >= 128) {
    _Float16* up16 = (_Float16*)d_ws;
    for (long row0 = 0; row0 < BATCH; row0 += chunk) {
      int rows = (int)((row0 + chunk <= BATCH) ? chunk : (BATCH - row0));
      dim3 g(FIVEH / 128, rows / 128);
      gemm_up<<<g, 256, 0, stream>>>(input, W, bvec, up16, (int)row0, rows);
      urnn_row<<<rows, 256, 0, stream>>>(up16, hx_real, hx_imag, beta, perm,
                                         (float*)d_out, (int)row0, (long)out_size, omode);
    }
  } else {
    urnn_fused<<<BATCH, 256, 0, stream>>>(input, W, bvec, hx_real, hx_imag, beta, perm,
                                          (float*)d_out, (long)out_size, omode);
  }
}